// Round 19
// baseline (2499.298 us; speedup 1.0000x reference)
//
#include <hip/hip_runtime.h>
#include <hip/hip_bf16.h>
#include <math.h>

#define D_F   64
#define IN_F  183     // 2*64 + 2*25 + 3 + 1 + 1
#define KS1   6       // layer-1 K tiles: 192 = 6*32 (padded from 183)
#define KS2   8       // layer-2/3 K tiles: 256 = 8*32
#define HID   256
#define HPITCH 264    // u16 per row: 528B; 528/16=33, 33%8==1 -> uniform bank spread
#define BM    32      // pairs per block (small block -> multi-block residency)
#define BLK   256     // 4 waves; wave w owns hidden dims [64w,64w+64) x all 32 pairs

typedef unsigned short u16;
typedef __attribute__((ext_vector_type(8))) short bf16x8;
typedef __attribute__((ext_vector_type(4))) float f32x4;

__device__ __forceinline__ u16 f2bf(float v) {
    __hip_bfloat16 h = __float2bfloat16(v);   // RNE
    u16 u; __builtin_memcpy(&u, &h, 2); return u;
}

// ---------------------------------------------------------------------------
// Pack W (K x 256 f32, row-major) into MFMA fragment order (bf16):
//   Wp[((mt*KSs + ks)*64 + lane)*8 + j] = W[ks*32 + 8*(lane>>4) + j][mt*16 + (lane&15)]
// Serves as the A-operand (W^T rows) in the transposed scheme.
// ---------------------------------------------------------------------------
__global__ void pack_w_kernel(const float* __restrict__ W, u16* __restrict__ Wp,
                              int K, int KSs)
{
    int g = blockIdx.x * 256 + threadIdx.x;
    int total = 16 * KSs * 64;
    if (g >= total) return;
    int lane = g & 63;
    int ks   = (g >> 6) % KSs;
    int mt   = (g >> 6) / KSs;
    int col  = mt * 16 + (lane & 15);
    int kb   = ks * 32 + 8 * (lane >> 4);
    u16 out[8];
    #pragma unroll
    for (int j = 0; j < 8; ++j) {
        int k = kb + j;
        out[j] = f2bf((k < K) ? W[(size_t)k * HID + col] : 0.0f);
    }
    *(bf16x8*)(Wp + (size_t)g * 8) = *(const bf16x8*)out;
}

// Pack W3 (256 x 3 f32): rows n<3 of W3^T, rest zero
__global__ void pack_w3_kernel(const float* __restrict__ W3, u16* __restrict__ W3p)
{
    int g = blockIdx.x * 256 + threadIdx.x;
    if (g >= KS2 * 64) return;
    int lane = g & 63;
    int ks   = g >> 6;
    int n    = lane & 15;
    int kb   = ks * 32 + 8 * (lane >> 4);
    u16 out[8];
    #pragma unroll
    for (int j = 0; j < 8; ++j)
        out[j] = f2bf((n < 3) ? W3[(size_t)(kb + j) * 3 + n] : 0.0f);
    *(bf16x8*)(W3p + (size_t)g * 8) = *(const bf16x8*)out;
}

// ---------------------------------------------------------------------------
// Small-block fat-wave transposed fused MLP, VGPR-capped for residency.
// Block = 32 pairs at one t (gridDim.y=T+1), 256 threads / 4 waves. Wave w
// owns hidden dims [64w,64w+64) x ALL 32 pairs: acc1[4 mtl][2 nt] +
// acc2[4][2] = 64 acc VGPRs.
// KEY CHANGE vs round 14 (same structure, 132 VGPR, 12% occupancy, 1525us):
// (a) __launch_bounds__(256,4) hard-caps VGPR at 128 (the 18-round residency
//     evidence: 256-thr blocks go multi-block/CU only at VGPR <= ~128;
//     round 14 missed the cliff by 4 registers);
// (b) L1/L2 weight-fragment arrays split into 2-mtl halves (wfr[2] not
//     wfr[4]) to shave ~8 live registers so the cap is met WITHOUT scratch
//     spill (round 4's lesson: a 60-reg overshoot spills catastrophically;
//     a ~4-reg delta reschedules).
// Double LDS buffer: bufA = x then h1; bufB = h2. 3 barriers per k.
// ---------------------------------------------------------------------------
__global__ __launch_bounds__(BLK, 4)
void mfp_mlp_mfma(const float* __restrict__ features,
                  const float* __restrict__ states,
                  const float* __restrict__ distances,
                  const float* __restrict__ W1,   // f32, for one-hot rows 178..180
                  const u16* __restrict__ W1p, const float* __restrict__ b1,
                  const u16* __restrict__ W2p, const float* __restrict__ b2,
                  const u16* __restrict__ W3p, const float* __restrict__ b3,
                  const int* __restrict__ pairs_i, const int* __restrict__ pairs_j,
                  float* __restrict__ cond,
                  int N, int T1s, int E, int T)
{
    __shared__ u16   bufA[BM * HPITCH];   // x, then h1 per k
    __shared__ u16   bufB[BM * HPITCH];   // h2 per k
    __shared__ int   s_pi[BM], s_pj[BM], s_e[BM], s_val[BM];
    __shared__ float s_dist[BM];

    const int tid = threadIdx.x;
    const int t   = blockIdx.y;
    const int nk  = (t == 0) ? 1 : 3;

    // ---- per-pair meta ----
    if (tid < BM) {
        int pe = blockIdx.x * BM + tid;
        int valid = (pe < E) ? 1 : 0;
        int e = valid ? pe : 0;
        int pi = pairs_i[e], pj = pairs_j[e];
        s_e[tid] = e; s_val[tid] = valid; s_pi[tid] = pi; s_pj[tid] = pj;
        s_dist[tid] = distances[(long long)pi * N + pj];
    }
    __syncthreads();

    // ---- assemble x rows (bf16) into bufA, one-hot cols (178..180) zeroed ----
    u16* xs = bufA;
    for (int idx = tid; idx < BM * 32; idx += BLK) {     // cols 0..127: features
        int m = idx >> 5;
        int q = idx & 31;
        int src = (q < 16) ? s_pi[m] : s_pj[m];
        int c4  = (q & 15) * 4;
        float4 f = *(const float4*)&features[(size_t)src * D_F + c4];
        int c = ((q < 16) ? 0 : 64) + c4;
        ushort4 o;
        o.x = f2bf(f.x); o.y = f2bf(f.y); o.z = f2bf(f.z); o.w = f2bf(f.w);
        *(ushort4*)(xs + m * HPITCH + c) = o;
    }
    for (int idx = tid; idx < BM * 64; idx += BLK) {     // cols 128..191
        int m = idx >> 6;
        int c = 128 + (idx & 63);
        float v;
        if (c < 178) {
            int cc = c - 128;
            int row = (cc < 25) ? s_pi[m] : s_pj[m];
            int c2  = (cc < 25) ? cc : (cc - 25);
            int l = c2 / 5;
            int s = c2 - l * 5;
            int tau = t - 4 + l;
            v = (tau >= 0) ? states[((size_t)row * T1s + tau) * 5 + s] : 0.0f;
        } else if (c == 181) {
            v = s_dist[m];
        } else if (c == 182) {
            v = (t == 0) ? 1.0f : 0.0f;
        } else {
            v = 0.0f;   // one-hot 178..180 and pad 183..191
        }
        xs[m * HPITCH + c] = f2bf(v);
    }
    __syncthreads();

    const int lane = tid & 63;
    const int w    = tid >> 6;     // wave id 0..3; hidden dims 64w..64w+63 (mt = 4w+mtl)
    const int lr   = lane & 15;
    const int lg   = lane >> 4;

    // ---- layer 1 (once): acc1 = W1^T . x^T, held across the k-loop ----
    // lane: pair m = 16*nt + lr ; hidden h = 16*(4w+mtl) + 4*lg + r
    f32x4 acc1[4][2];
    #pragma unroll
    for (int i = 0; i < 4; ++i)
        #pragma unroll
        for (int j = 0; j < 2; ++j)
            acc1[i][j] = (f32x4){0.f, 0.f, 0.f, 0.f};

    for (int ks = 0; ks < KS1; ++ks) {
        bf16x8 xfr[2];
        #pragma unroll
        for (int nt = 0; nt < 2; ++nt)
            xfr[nt] = *(const bf16x8*)(xs + (16 * nt + lr) * HPITCH + ks * 32 + 8 * lg);
        #pragma unroll
        for (int mh = 0; mh < 2; ++mh) {           // 2-mtl halves: wfr[2] live, not wfr[4]
            bf16x8 wfr[2];
            #pragma unroll
            for (int ml = 0; ml < 2; ++ml)
                wfr[ml] = *(const bf16x8*)(W1p + (((size_t)(4 * w + 2 * mh + ml) * KS1 + ks) * 64 + lane) * 8);
            #pragma unroll
            for (int ml = 0; ml < 2; ++ml)
                #pragma unroll
                for (int nt = 0; nt < 2; ++nt)
                    acc1[2 * mh + ml][nt] = __builtin_amdgcn_mfma_f32_16x16x32_bf16(wfr[ml], xfr[nt], acc1[2 * mh + ml][nt], 0, 0, 0);
        }
    }

    __syncthreads();   // all x reads done; bufA becomes the h1 buffer

    // ---- k-loop (3 barriers per k) ----
    for (int k = 0; k < nk; ++k) {
        // h1_k = relu(acc1 + b1 + W1[178+k]) -> bufA[m][h], b64 stores
        #pragma unroll
        for (int mtl = 0; mtl < 4; ++mtl) {
            int h0 = 16 * (4 * w + mtl) + 4 * lg;
            f32x4 b1q = *(const f32x4*)&b1[h0];
            f32x4 ohq = *(const f32x4*)&W1[(size_t)(178 + k) * HID + h0];
            #pragma unroll
            for (int nt = 0; nt < 2; ++nt) {
                ushort4 p;
                p.x = f2bf(fmaxf(acc1[mtl][nt][0] + b1q[0] + ohq[0], 0.0f));
                p.y = f2bf(fmaxf(acc1[mtl][nt][1] + b1q[1] + ohq[1], 0.0f));
                p.z = f2bf(fmaxf(acc1[mtl][nt][2] + b1q[2] + ohq[2], 0.0f));
                p.w = f2bf(fmaxf(acc1[mtl][nt][3] + b1q[3] + ohq[3], 0.0f));
                *(ushort4*)(bufA + (16 * nt + lr) * HPITCH + h0) = p;
            }
        }
        __syncthreads();   // h1 ready

        // layer 2: acc2 = W2^T . h1^T (2-mtl halves keep wfr[2] live)
        f32x4 acc2[4][2];
        #pragma unroll
        for (int i = 0; i < 4; ++i)
            #pragma unroll
            for (int j = 0; j < 2; ++j)
                acc2[i][j] = (f32x4){0.f, 0.f, 0.f, 0.f};

        for (int ks = 0; ks < KS2; ++ks) {
            bf16x8 hfr[2];
            #pragma unroll
            for (int nt = 0; nt < 2; ++nt)
                hfr[nt] = *(const bf16x8*)(bufA + (16 * nt + lr) * HPITCH + ks * 32 + 8 * lg);
            #pragma unroll
            for (int mh = 0; mh < 2; ++mh) {
                bf16x8 wfr[2];
                #pragma unroll
                for (int ml = 0; ml < 2; ++ml)
                    wfr[ml] = *(const bf16x8*)(W2p + (((size_t)(4 * w + 2 * mh + ml) * KS2 + ks) * 64 + lane) * 8);
                #pragma unroll
                for (int ml = 0; ml < 2; ++ml)
                    #pragma unroll
                    for (int nt = 0; nt < 2; ++nt)
                        acc2[2 * mh + ml][nt] = __builtin_amdgcn_mfma_f32_16x16x32_bf16(wfr[ml], hfr[nt], acc2[2 * mh + ml][nt], 0, 0, 0);
            }
        }

        // h2 = relu(acc2 + b2) -> bufB (prev k's layer-3 reads finished at the
        // end-of-iteration barrier)
        #pragma unroll
        for (int mtl = 0; mtl < 4; ++mtl) {
            int h0 = 16 * (4 * w + mtl) + 4 * lg;
            f32x4 b2q = *(const f32x4*)&b2[h0];
            #pragma unroll
            for (int nt = 0; nt < 2; ++nt) {
                ushort4 p;
                p.x = f2bf(fmaxf(acc2[mtl][nt][0] + b2q[0], 0.0f));
                p.y = f2bf(fmaxf(acc2[mtl][nt][1] + b2q[1], 0.0f));
                p.z = f2bf(fmaxf(acc2[mtl][nt][2] + b2q[2], 0.0f));
                p.w = f2bf(fmaxf(acc2[mtl][nt][3] + b2q[3], 0.0f));
                *(ushort4*)(bufB + (16 * nt + lr) * HPITCH + h0) = p;
            }
        }
        __syncthreads();   // h2 ready (also: h1 reads done -> bufA reusable)

        // layer 3: logits^T = W3^T . h2^T; waves 0..1, wave w -> pairs 16w..16w+15
        if (w < 2) {
            f32x4 acc3 = (f32x4){0.f, 0.f, 0.f, 0.f};
            for (int ks = 0; ks < KS2; ++ks) {
                bf16x8 hfr = *(const bf16x8*)(bufB + (16 * w + lr) * HPITCH + ks * 32 + 8 * lg);
                bf16x8 wfr = *(const bf16x8*)(W3p + ((size_t)(ks * 64 + lane)) * 8);
                acc3 = __builtin_amdgcn_mfma_f32_16x16x32_bf16(wfr, hfr, acc3, 0, 0, 0);
            }
            // lane (lg==0, lr): acc3[r] = logit n=r of pair m = 16w+lr
            int m = 16 * w + lr;
            if (lg == 0 && s_val[m]) {
                float l0 = acc3[0] + b3[0];
                float l1 = acc3[1] + b3[1];
                float l2 = acc3[2] + b3[2];
                float mx = fmaxf(l0, fmaxf(l1, l2));
                float e0 = expf(l0 - mx), e1 = expf(l1 - mx), e2 = expf(l2 - mx);
                float inv = 1.0f / (e0 + e1 + e2);
                float p0 = e0 * inv, p1 = e1 * inv, p2 = e2 * inv;
                size_t base = ((size_t)t * E + s_e[m]) * 9;
                if (t == 0) {
                    #pragma unroll
                    for (int kb = 0; kb < 3; ++kb) {
                        cond[base + kb * 3 + 0] = p0;
                        cond[base + kb * 3 + 1] = p1;
                        cond[base + kb * 3 + 2] = p2;
                    }
                } else {
                    cond[base + k * 3 + 0] = p0;
                    cond[base + k * 3 + 1] = p1;
                    cond[base + k * 3 + 2] = p2;
                }
            }
        }
        __syncthreads();   // bufB reads done; next k's h2 write may proceed
    }
}

// ---------------------------------------------------------------------------
// Marginal chain: m_t = m_{t-1} @ cond[t]
// ---------------------------------------------------------------------------
__global__ __launch_bounds__(256)
void mfp_marg_kernel(const float* __restrict__ cond,
                     float* __restrict__ marg,
                     int E, int T)
{
    int e = blockIdx.x * 256 + threadIdx.x;
    if (e >= E) return;
    const float* c0 = &cond[(size_t)e * 9];
    float m0 = c0[0], m1 = c0[1], m2 = c0[2];
    marg[(size_t)e * 3 + 0] = m0;
    marg[(size_t)e * 3 + 1] = m1;
    marg[(size_t)e * 3 + 2] = m2;
    for (int t = 1; t <= T; ++t) {
        const float* c9 = &cond[((size_t)t * E + e) * 9];
        float n0 = m0 * c9[0] + m1 * c9[3] + m2 * c9[6];
        float n1 = m0 * c9[1] + m1 * c9[4] + m2 * c9[7];
        float n2 = m0 * c9[2] + m1 * c9[5] + m2 * c9[8];
        m0 = n0; m1 = n1; m2 = n2;
        float* mo = &marg[((size_t)t * E + e) * 3];
        mo[0] = m0; mo[1] = m1; mo[2] = m2;
    }
}

// ---------------------------------------------------------------------------
extern "C" void kernel_launch(void* const* d_in, const int* in_sizes, int n_in,
                              void* d_out, int out_size, void* d_ws, size_t ws_size,
                              hipStream_t stream) {
    const float* features  = (const float*)d_in[0];
    const float* states    = (const float*)d_in[1];
    const float* distances = (const float*)d_in[2];
    const float* W1 = (const float*)d_in[3];
    const float* b1 = (const float*)d_in[4];
    const float* W2 = (const float*)d_in[5];
    const float* b2 = (const float*)d_in[6];
    const float* W3 = (const float*)d_in[7];
    const float* b3 = (const float*)d_in[8];
    const int* pairs_i = (const int*)d_in[9];
    const int* pairs_j = (const int*)d_in[10];

    const int N   = in_sizes[0] / D_F;             // 2000
    const int T1s = in_sizes[1] / (N * 5);         // 11
    const int E   = in_sizes[9];                   // 100000
    const int T   = out_size / (12 * E) - 1;       // 10

    float* cond = (float*)d_out;                            // (T+1, E, 3, 3)
    float* marg = (float*)d_out + (size_t)(T + 1) * E * 9;  // (T+1, E, 3)

    u16* W1p = (u16*)d_ws;                                  // 16*KS1*64*8 elems
    u16* W2p = W1p + 16 * KS1 * 64 * 8;                     // 16*KS2*64*8 elems
    u16* W3p = W2p + 16 * KS2 * 64 * 8;                     // KS2*64*8 elems

    {
        int g1 = 16 * KS1 * 64;
        int g2 = 16 * KS2 * 64;
        int g3 = KS2 * 64;
        pack_w_kernel<<<(g1 + 255) / 256, 256, 0, stream>>>(W1, W1p, IN_F, KS1);
        pack_w_kernel<<<(g2 + 255) / 256, 256, 0, stream>>>(W2, W2p, HID, KS2);
        pack_w3_kernel<<<(g3 + 255) / 256, 256, 0, stream>>>(W3, W3p);
    }

    dim3 grid((E + BM - 1) / BM, T + 1);
    mfp_mlp_mfma<<<grid, BLK, 0, stream>>>(
        features, states, distances, W1, W1p, b1, W2p, b2, W3p, b3,
        pairs_i, pairs_j, cond, N, T1s, E, T);

    mfp_marg_kernel<<<(E + 255) / 256, 256, 0, stream>>>(cond, marg, E, T);
}

// Round 20
// 898.359 us; speedup vs baseline: 2.7821x; 2.7821x over previous
//
#include <hip/hip_runtime.h>
#include <hip/hip_bf16.h>
#include <math.h>

#define D_F   64
#define IN_F  183     // 2*64 + 2*25 + 3 + 1 + 1
#define KS1   6       // layer-1 K tiles: 192 = 6*32 (padded from 183)
#define KS2   8       // layer-2/3 K tiles: 256 = 8*32
#define HID   256
#define HPITCH 264    // u16 per row: 528B; 528/16=33, 33%8==1 -> uniform bank spread
#define BM    32      // pairs per block (small block -> multi-block residency)
#define BLK   256     // 4 waves; wave w owns hidden dims [64w,64w+64) x all 32 pairs

typedef unsigned short u16;
typedef __attribute__((ext_vector_type(8))) short bf16x8;
typedef __attribute__((ext_vector_type(4))) float f32x4;

__device__ __forceinline__ u16 f2bf(float v) {
    __hip_bfloat16 h = __float2bfloat16(v);   // RNE
    u16 u; __builtin_memcpy(&u, &h, 2); return u;
}

// ---------------------------------------------------------------------------
// Pack W (K x 256 f32, row-major) into MFMA fragment order (bf16):
//   Wp[((mt*KSs + ks)*64 + lane)*8 + j] = W[ks*32 + 8*(lane>>4) + j][mt*16 + (lane&15)]
// Serves as the A-operand (W^T rows) in the transposed scheme.
// ---------------------------------------------------------------------------
__global__ void pack_w_kernel(const float* __restrict__ W, u16* __restrict__ Wp,
                              int K, int KSs)
{
    int g = blockIdx.x * 256 + threadIdx.x;
    int total = 16 * KSs * 64;
    if (g >= total) return;
    int lane = g & 63;
    int ks   = (g >> 6) % KSs;
    int mt   = (g >> 6) / KSs;
    int col  = mt * 16 + (lane & 15);
    int kb   = ks * 32 + 8 * (lane >> 4);
    u16 out[8];
    #pragma unroll
    for (int j = 0; j < 8; ++j) {
        int k = kb + j;
        out[j] = f2bf((k < K) ? W[(size_t)k * HID + col] : 0.0f);
    }
    *(bf16x8*)(Wp + (size_t)g * 8) = *(const bf16x8*)out;
}

// Pack W3 (256 x 3 f32): rows n<3 of W3^T, rest zero
__global__ void pack_w3_kernel(const float* __restrict__ W3, u16* __restrict__ W3p)
{
    int g = blockIdx.x * 256 + threadIdx.x;
    if (g >= KS2 * 64) return;
    int lane = g & 63;
    int ks   = g >> 6;
    int n    = lane & 15;
    int kb   = ks * 32 + 8 * (lane >> 4);
    u16 out[8];
    #pragma unroll
    for (int j = 0; j < 8; ++j)
        out[j] = f2bf((n < 3) ? W3[(size_t)(kb + j) * 3 + n] : 0.0f);
    *(bf16x8*)(W3p + (size_t)g * 8) = *(const bf16x8*)out;
}

// ---------------------------------------------------------------------------
// Small-block fat-wave transposed fused MLP, VGPR-capped at 128 for residency.
// Block = 32 pairs at one t (gridDim.y=T+1), 256 threads / 4 waves. Wave w
// owns hidden dims [64w,64w+64) x ALL 32 pairs: acc1[4 mtl][2 nt] +
// acc2[4][2] = 64 acc VGPRs; live set ~130 with bare bounds (round 14: 132).
// EMPIRICAL launch-bounds map (19 rounds): 2nd-arg=4 => cap 64 (round 19:
// spilled 65 regs, 10.5GB scratch); 2nd-arg=2 => cap 128 (round 4: exactly
// 128); VGPR<=128 => up to 4 blocks of 256thr co-resident (round 19: 47%
// occupancy); VGPR>128 => 1 block (rounds 13/14). Here the overshoot is only
// ~2-6 regs, so (256,2) should squeeze to 128 by rescheduling, not spilling.
// Double LDS buffer: bufA = x then h1; bufB = h2. 3 barriers per k.
// ---------------------------------------------------------------------------
__global__ __launch_bounds__(BLK, 2)
void mfp_mlp_mfma(const float* __restrict__ features,
                  const float* __restrict__ states,
                  const float* __restrict__ distances,
                  const float* __restrict__ W1,   // f32, for one-hot rows 178..180
                  const u16* __restrict__ W1p, const float* __restrict__ b1,
                  const u16* __restrict__ W2p, const float* __restrict__ b2,
                  const u16* __restrict__ W3p, const float* __restrict__ b3,
                  const int* __restrict__ pairs_i, const int* __restrict__ pairs_j,
                  float* __restrict__ cond,
                  int N, int T1s, int E, int T)
{
    __shared__ u16   bufA[BM * HPITCH];   // x, then h1 per k
    __shared__ u16   bufB[BM * HPITCH];   // h2 per k
    __shared__ int   s_pi[BM], s_pj[BM], s_e[BM], s_val[BM];
    __shared__ float s_dist[BM];

    const int tid = threadIdx.x;
    const int t   = blockIdx.y;
    const int nk  = (t == 0) ? 1 : 3;

    // ---- per-pair meta ----
    if (tid < BM) {
        int pe = blockIdx.x * BM + tid;
        int valid = (pe < E) ? 1 : 0;
        int e = valid ? pe : 0;
        int pi = pairs_i[e], pj = pairs_j[e];
        s_e[tid] = e; s_val[tid] = valid; s_pi[tid] = pi; s_pj[tid] = pj;
        s_dist[tid] = distances[(long long)pi * N + pj];
    }
    __syncthreads();

    // ---- assemble x rows (bf16) into bufA, one-hot cols (178..180) zeroed ----
    u16* xs = bufA;
    for (int idx = tid; idx < BM * 32; idx += BLK) {     // cols 0..127: features
        int m = idx >> 5;
        int q = idx & 31;
        int src = (q < 16) ? s_pi[m] : s_pj[m];
        int c4  = (q & 15) * 4;
        float4 f = *(const float4*)&features[(size_t)src * D_F + c4];
        int c = ((q < 16) ? 0 : 64) + c4;
        ushort4 o;
        o.x = f2bf(f.x); o.y = f2bf(f.y); o.z = f2bf(f.z); o.w = f2bf(f.w);
        *(ushort4*)(xs + m * HPITCH + c) = o;
    }
    for (int idx = tid; idx < BM * 64; idx += BLK) {     // cols 128..191
        int m = idx >> 6;
        int c = 128 + (idx & 63);
        float v;
        if (c < 178) {
            int cc = c - 128;
            int row = (cc < 25) ? s_pi[m] : s_pj[m];
            int c2  = (cc < 25) ? cc : (cc - 25);
            int l = c2 / 5;
            int s = c2 - l * 5;
            int tau = t - 4 + l;
            v = (tau >= 0) ? states[((size_t)row * T1s + tau) * 5 + s] : 0.0f;
        } else if (c == 181) {
            v = s_dist[m];
        } else if (c == 182) {
            v = (t == 0) ? 1.0f : 0.0f;
        } else {
            v = 0.0f;   // one-hot 178..180 and pad 183..191
        }
        xs[m * HPITCH + c] = f2bf(v);
    }
    __syncthreads();

    const int lane = tid & 63;
    const int w    = tid >> 6;     // wave id 0..3; hidden dims 64w..64w+63 (mt = 4w+mtl)
    const int lr   = lane & 15;
    const int lg   = lane >> 4;

    // ---- layer 1 (once): acc1 = W1^T . x^T, held across the k-loop ----
    // lane: pair m = 16*nt + lr ; hidden h = 16*(4w+mtl) + 4*lg + r
    f32x4 acc1[4][2];
    #pragma unroll
    for (int i = 0; i < 4; ++i)
        #pragma unroll
        for (int j = 0; j < 2; ++j)
            acc1[i][j] = (f32x4){0.f, 0.f, 0.f, 0.f};

    for (int ks = 0; ks < KS1; ++ks) {
        bf16x8 xfr[2];
        #pragma unroll
        for (int nt = 0; nt < 2; ++nt)
            xfr[nt] = *(const bf16x8*)(xs + (16 * nt + lr) * HPITCH + ks * 32 + 8 * lg);
        #pragma unroll
        for (int mh = 0; mh < 2; ++mh) {           // 2-mtl halves: wfr[2] live, not wfr[4]
            bf16x8 wfr[2];
            #pragma unroll
            for (int ml = 0; ml < 2; ++ml)
                wfr[ml] = *(const bf16x8*)(W1p + (((size_t)(4 * w + 2 * mh + ml) * KS1 + ks) * 64 + lane) * 8);
            #pragma unroll
            for (int ml = 0; ml < 2; ++ml)
                #pragma unroll
                for (int nt = 0; nt < 2; ++nt)
                    acc1[2 * mh + ml][nt] = __builtin_amdgcn_mfma_f32_16x16x32_bf16(wfr[ml], xfr[nt], acc1[2 * mh + ml][nt], 0, 0, 0);
        }
    }

    __syncthreads();   // all x reads done; bufA becomes the h1 buffer

    // ---- k-loop (3 barriers per k) ----
    for (int k = 0; k < nk; ++k) {
        // h1_k = relu(acc1 + b1 + W1[178+k]) -> bufA[m][h], b64 stores
        #pragma unroll
        for (int mtl = 0; mtl < 4; ++mtl) {
            int h0 = 16 * (4 * w + mtl) + 4 * lg;
            f32x4 b1q = *(const f32x4*)&b1[h0];
            f32x4 ohq = *(const f32x4*)&W1[(size_t)(178 + k) * HID + h0];
            #pragma unroll
            for (int nt = 0; nt < 2; ++nt) {
                ushort4 p;
                p.x = f2bf(fmaxf(acc1[mtl][nt][0] + b1q[0] + ohq[0], 0.0f));
                p.y = f2bf(fmaxf(acc1[mtl][nt][1] + b1q[1] + ohq[1], 0.0f));
                p.z = f2bf(fmaxf(acc1[mtl][nt][2] + b1q[2] + ohq[2], 0.0f));
                p.w = f2bf(fmaxf(acc1[mtl][nt][3] + b1q[3] + ohq[3], 0.0f));
                *(ushort4*)(bufA + (16 * nt + lr) * HPITCH + h0) = p;
            }
        }
        __syncthreads();   // h1 ready

        // layer 2: acc2 = W2^T . h1^T (2-mtl halves keep wfr[2] live)
        f32x4 acc2[4][2];
        #pragma unroll
        for (int i = 0; i < 4; ++i)
            #pragma unroll
            for (int j = 0; j < 2; ++j)
                acc2[i][j] = (f32x4){0.f, 0.f, 0.f, 0.f};

        for (int ks = 0; ks < KS2; ++ks) {
            bf16x8 hfr[2];
            #pragma unroll
            for (int nt = 0; nt < 2; ++nt)
                hfr[nt] = *(const bf16x8*)(bufA + (16 * nt + lr) * HPITCH + ks * 32 + 8 * lg);
            #pragma unroll
            for (int mh = 0; mh < 2; ++mh) {
                bf16x8 wfr[2];
                #pragma unroll
                for (int ml = 0; ml < 2; ++ml)
                    wfr[ml] = *(const bf16x8*)(W2p + (((size_t)(4 * w + 2 * mh + ml) * KS2 + ks) * 64 + lane) * 8);
                #pragma unroll
                for (int ml = 0; ml < 2; ++ml)
                    #pragma unroll
                    for (int nt = 0; nt < 2; ++nt)
                        acc2[2 * mh + ml][nt] = __builtin_amdgcn_mfma_f32_16x16x32_bf16(wfr[ml], hfr[nt], acc2[2 * mh + ml][nt], 0, 0, 0);
            }
        }

        // h2 = relu(acc2 + b2) -> bufB (prev k's layer-3 reads finished at the
        // end-of-iteration barrier)
        #pragma unroll
        for (int mtl = 0; mtl < 4; ++mtl) {
            int h0 = 16 * (4 * w + mtl) + 4 * lg;
            f32x4 b2q = *(const f32x4*)&b2[h0];
            #pragma unroll
            for (int nt = 0; nt < 2; ++nt) {
                ushort4 p;
                p.x = f2bf(fmaxf(acc2[mtl][nt][0] + b2q[0], 0.0f));
                p.y = f2bf(fmaxf(acc2[mtl][nt][1] + b2q[1], 0.0f));
                p.z = f2bf(fmaxf(acc2[mtl][nt][2] + b2q[2], 0.0f));
                p.w = f2bf(fmaxf(acc2[mtl][nt][3] + b2q[3], 0.0f));
                *(ushort4*)(bufB + (16 * nt + lr) * HPITCH + h0) = p;
            }
        }
        __syncthreads();   // h2 ready (also: h1 reads done -> bufA reusable)

        // layer 3: logits^T = W3^T . h2^T; waves 0..1, wave w -> pairs 16w..16w+15
        if (w < 2) {
            f32x4 acc3 = (f32x4){0.f, 0.f, 0.f, 0.f};
            for (int ks = 0; ks < KS2; ++ks) {
                bf16x8 hfr = *(const bf16x8*)(bufB + (16 * w + lr) * HPITCH + ks * 32 + 8 * lg);
                bf16x8 wfr = *(const bf16x8*)(W3p + ((size_t)(ks * 64 + lane)) * 8);
                acc3 = __builtin_amdgcn_mfma_f32_16x16x32_bf16(wfr, hfr, acc3, 0, 0, 0);
            }
            // lane (lg==0, lr): acc3[r] = logit n=r of pair m = 16w+lr
            int m = 16 * w + lr;
            if (lg == 0 && s_val[m]) {
                float l0 = acc3[0] + b3[0];
                float l1 = acc3[1] + b3[1];
                float l2 = acc3[2] + b3[2];
                float mx = fmaxf(l0, fmaxf(l1, l2));
                float e0 = expf(l0 - mx), e1 = expf(l1 - mx), e2 = expf(l2 - mx);
                float inv = 1.0f / (e0 + e1 + e2);
                float p0 = e0 * inv, p1 = e1 * inv, p2 = e2 * inv;
                size_t base = ((size_t)t * E + s_e[m]) * 9;
                if (t == 0) {
                    #pragma unroll
                    for (int kb = 0; kb < 3; ++kb) {
                        cond[base + kb * 3 + 0] = p0;
                        cond[base + kb * 3 + 1] = p1;
                        cond[base + kb * 3 + 2] = p2;
                    }
                } else {
                    cond[base + k * 3 + 0] = p0;
                    cond[base + k * 3 + 1] = p1;
                    cond[base + k * 3 + 2] = p2;
                }
            }
        }
        __syncthreads();   // bufB reads done; next k's h2 write may proceed
    }
}

// ---------------------------------------------------------------------------
// Marginal chain: m_t = m_{t-1} @ cond[t]
// ---------------------------------------------------------------------------
__global__ __launch_bounds__(256)
void mfp_marg_kernel(const float* __restrict__ cond,
                     float* __restrict__ marg,
                     int E, int T)
{
    int e = blockIdx.x * 256 + threadIdx.x;
    if (e >= E) return;
    const float* c0 = &cond[(size_t)e * 9];
    float m0 = c0[0], m1 = c0[1], m2 = c0[2];
    marg[(size_t)e * 3 + 0] = m0;
    marg[(size_t)e * 3 + 1] = m1;
    marg[(size_t)e * 3 + 2] = m2;
    for (int t = 1; t <= T; ++t) {
        const float* c9 = &cond[((size_t)t * E + e) * 9];
        float n0 = m0 * c9[0] + m1 * c9[3] + m2 * c9[6];
        float n1 = m0 * c9[1] + m1 * c9[4] + m2 * c9[7];
        float n2 = m0 * c9[2] + m1 * c9[5] + m2 * c9[8];
        m0 = n0; m1 = n1; m2 = n2;
        float* mo = &marg[((size_t)t * E + e) * 3];
        mo[0] = m0; mo[1] = m1; mo[2] = m2;
    }
}

// ---------------------------------------------------------------------------
extern "C" void kernel_launch(void* const* d_in, const int* in_sizes, int n_in,
                              void* d_out, int out_size, void* d_ws, size_t ws_size,
                              hipStream_t stream) {
    const float* features  = (const float*)d_in[0];
    const float* states    = (const float*)d_in[1];
    const float* distances = (const float*)d_in[2];
    const float* W1 = (const float*)d_in[3];
    const float* b1 = (const float*)d_in[4];
    const float* W2 = (const float*)d_in[5];
    const float* b2 = (const float*)d_in[6];
    const float* W3 = (const float*)d_in[7];
    const float* b3 = (const float*)d_in[8];
    const int* pairs_i = (const int*)d_in[9];
    const int* pairs_j = (const int*)d_in[10];

    const int N   = in_sizes[0] / D_F;             // 2000
    const int T1s = in_sizes[1] / (N * 5);         // 11
    const int E   = in_sizes[9];                   // 100000
    const int T   = out_size / (12 * E) - 1;       // 10

    float* cond = (float*)d_out;                            // (T+1, E, 3, 3)
    float* marg = (float*)d_out + (size_t)(T + 1) * E * 9;  // (T+1, E, 3)

    u16* W1p = (u16*)d_ws;                                  // 16*KS1*64*8 elems
    u16* W2p = W1p + 16 * KS1 * 64 * 8;                     // 16*KS2*64*8 elems
    u16* W3p = W2p + 16 * KS2 * 64 * 8;                     // KS2*64*8 elems

    {
        int g1 = 16 * KS1 * 64;
        int g2 = 16 * KS2 * 64;
        int g3 = KS2 * 64;
        pack_w_kernel<<<(g1 + 255) / 256, 256, 0, stream>>>(W1, W1p, IN_F, KS1);
        pack_w_kernel<<<(g2 + 255) / 256, 256, 0, stream>>>(W2, W2p, HID, KS2);
        pack_w3_kernel<<<(g3 + 255) / 256, 256, 0, stream>>>(W3, W3p);
    }

    dim3 grid((E + BM - 1) / BM, T + 1);
    mfp_mlp_mfma<<<grid, BLK, 0, stream>>>(
        features, states, distances, W1, W1p, b1, W2p, b2, W3p, b3,
        pairs_i, pairs_j, cond, N, T1s, E, T);

    mfp_marg_kernel<<<(E + 255) / 256, 256, 0, stream>>>(cond, marg, E, T);
}

// Round 21
// 861.649 us; speedup vs baseline: 2.9006x; 1.0426x over previous
//
#include <hip/hip_runtime.h>
#include <hip/hip_bf16.h>
#include <math.h>

#define D_F   64
#define IN_F  183     // 2*64 + 2*25 + 3 + 1 + 1
#define KS1   6       // layer-1 K tiles: 192 = 6*32 (padded from 183)
#define KS2   8       // layer-2/3 K tiles: 256 = 8*32
#define HID   256
#define HPITCH 264    // u16 per row: 528B; 528/16=33, 33%8==1 -> uniform bank spread
#define BM    64      // pairs per block
#define BLK   512     // 8 waves; wave w owns hidden tiles {2w,2w+1} x all 64 pairs

typedef unsigned short u16;
typedef __attribute__((ext_vector_type(8))) short bf16x8;
typedef __attribute__((ext_vector_type(4))) float f32x4;

__device__ __forceinline__ u16 f2bf(float v) {
    __hip_bfloat16 h = __float2bfloat16(v);   // RNE
    u16 u; __builtin_memcpy(&u, &h, 2); return u;
}

// ---------------------------------------------------------------------------
// Pack W (K x 256 f32, row-major) into MFMA fragment order (bf16):
//   Wp[((mt*KSs + ks)*64 + lane)*8 + j] = W[ks*32 + 8*(lane>>4) + j][mt*16 + (lane&15)]
// Serves as the A-operand (W^T rows) in the transposed scheme.
// ---------------------------------------------------------------------------
__global__ void pack_w_kernel(const float* __restrict__ W, u16* __restrict__ Wp,
                              int K, int KSs)
{
    int g = blockIdx.x * 256 + threadIdx.x;
    int total = 16 * KSs * 64;
    if (g >= total) return;
    int lane = g & 63;
    int ks   = (g >> 6) % KSs;
    int mt   = (g >> 6) / KSs;
    int col  = mt * 16 + (lane & 15);
    int kb   = ks * 32 + 8 * (lane >> 4);
    u16 out[8];
    #pragma unroll
    for (int j = 0; j < 8; ++j) {
        int k = kb + j;
        out[j] = f2bf((k < K) ? W[(size_t)k * HID + col] : 0.0f);
    }
    *(bf16x8*)(Wp + (size_t)g * 8) = *(const bf16x8*)out;
}

// Pack W3 (256 x 3 f32): rows n<3 of W3^T, rest zero
__global__ void pack_w3_kernel(const float* __restrict__ W3, u16* __restrict__ W3p)
{
    int g = blockIdx.x * 256 + threadIdx.x;
    if (g >= KS2 * 64) return;
    int lane = g & 63;
    int ks   = g >> 6;
    int n    = lane & 15;
    int kb   = ks * 32 + 8 * (lane >> 4);
    u16 out[8];
    #pragma unroll
    for (int j = 0; j < 8; ++j)
        out[j] = f2bf((n < 3) ? W3[(size_t)(kb + j) * 3 + n] : 0.0f);
    *(bf16x8*)(W3p + (size_t)g * 8) = *(const bf16x8*)out;
}

// ---------------------------------------------------------------------------
// FINAL champion (round 18, 862us): transposed pair-block fused MLP +
// pipelined h1(k+1) + all-wave layer-3.
// Block = 64 pairs at one t (gridDim.y=T+1), 8 waves; wave w owns hidden
// tiles {2w,2w+1} (dims 32w..32w+31) x all 64 pairs: acc[2 mtl][4 nt].
// h1(k+1) is written at the TOP of iteration k (independent given acc1) so
// its VALU/ds_write latency hides under layer-2's loads+MFMAs. Triple LDS
// buffer: buf0 = x then h1(odd k); buf1 = h1(even k); hsB = h2. 2 barriers/k.
// Layer 3 split across ALL 8 waves: wave (a=w&3, half=w>>2) computes the
// K-half [128*half,128*half+128) for pairs 16a..16a+15 (4 chained MFMAs);
// upper waves stash partial logits in s_l3; the existing end-of-k barrier
// publishes; lower waves sum + softmax.
// 20-round conclusion: every 8-waves/CU packaging converges to 860-900us
// (latency-bound phase chain; MFMA ~25%, VALU ~30%, no pipe saturated);
// 16 waves/CU is unreachable (512-thr never co-resides >=2 blocks; 256-thr
// x4 requires VGPR<=64 which spills the held accumulators). This config is
// the family optimum. Bare __launch_bounds__(512): 128 VGPR, no spill.
// ---------------------------------------------------------------------------
__global__ __launch_bounds__(BLK)
void mfp_mlp_mfma(const float* __restrict__ features,
                  const float* __restrict__ states,
                  const float* __restrict__ distances,
                  const float* __restrict__ W1,   // f32, for one-hot rows 178..180
                  const u16* __restrict__ W1p, const float* __restrict__ b1,
                  const u16* __restrict__ W2p, const float* __restrict__ b2,
                  const u16* __restrict__ W3p, const float* __restrict__ b3,
                  const int* __restrict__ pairs_i, const int* __restrict__ pairs_j,
                  float* __restrict__ cond,
                  int N, int T1s, int E, int T)
{
    extern __shared__ char smem[];
    u16* buf0 = (u16*)smem;              // [64][HPITCH]: x, then h1 for odd k
    u16* buf1 = buf0 + BM * HPITCH;      // [64][HPITCH]: h1 for even k
    u16* hsB  = buf1 + BM * HPITCH;      // [64][HPITCH]: h2
    __shared__ int   s_pi[BM], s_pj[BM], s_e[BM], s_val[BM];
    __shared__ float s_dist[BM];
    __shared__ float s_l3[4][16][3];     // upper-wave partial logits

    const int tid = threadIdx.x;
    const int t   = blockIdx.y;
    const int nk  = (t == 0) ? 1 : 3;

    // ---- per-pair meta ----
    if (tid < BM) {
        int pe = blockIdx.x * BM + tid;
        int valid = (pe < E) ? 1 : 0;
        int e = valid ? pe : 0;
        int pi = pairs_i[e], pj = pairs_j[e];
        s_e[tid] = e; s_val[tid] = valid; s_pi[tid] = pi; s_pj[tid] = pj;
        s_dist[tid] = distances[(long long)pi * N + pj];
    }
    __syncthreads();

    // ---- assemble x rows (bf16) into buf0, one-hot cols (178..180) zeroed ----
    u16* xs = buf0;
    for (int idx = tid; idx < BM * 32; idx += BLK) {     // cols 0..127: features
        int m = idx >> 5;
        int q = idx & 31;
        int src = (q < 16) ? s_pi[m] : s_pj[m];
        int c4  = (q & 15) * 4;
        float4 f = *(const float4*)&features[(size_t)src * D_F + c4];
        int c = ((q < 16) ? 0 : 64) + c4;
        ushort4 o;
        o.x = f2bf(f.x); o.y = f2bf(f.y); o.z = f2bf(f.z); o.w = f2bf(f.w);
        *(ushort4*)(xs + m * HPITCH + c) = o;
    }
    for (int idx = tid; idx < BM * 64; idx += BLK) {     // cols 128..191
        int m = idx >> 6;
        int c = 128 + (idx & 63);
        float v;
        if (c < 178) {
            int cc = c - 128;
            int row = (cc < 25) ? s_pi[m] : s_pj[m];
            int c2  = (cc < 25) ? cc : (cc - 25);
            int l = c2 / 5;
            int s = c2 - l * 5;
            int tau = t - 4 + l;
            v = (tau >= 0) ? states[((size_t)row * T1s + tau) * 5 + s] : 0.0f;
        } else if (c == 181) {
            v = s_dist[m];
        } else if (c == 182) {
            v = (t == 0) ? 1.0f : 0.0f;
        } else {
            v = 0.0f;   // one-hot 178..180 and pad 183..191
        }
        xs[m * HPITCH + c] = f2bf(v);
    }
    __syncthreads();

    const int lane = tid & 63;
    const int w    = tid >> 6;     // wave id 0..7
    const int lr   = lane & 15;
    const int lg   = lane >> 4;
    // wave w owns hidden tiles mt = 2w, 2w+1 (hidden dims 32w .. 32w+31)

    // ---- layer 1 (once): acc1 = W1^T . x^T, held across the k-loop ----
    // lane: pair m = 16*nt + lr ; hidden h = 16*(2w+mtl) + 4*lg + r
    f32x4 acc1[2][4];
    #pragma unroll
    for (int a = 0; a < 2; ++a)
        #pragma unroll
        for (int b = 0; b < 4; ++b)
            acc1[a][b] = (f32x4){0.f, 0.f, 0.f, 0.f};

    for (int ks = 0; ks < KS1; ++ks) {
        bf16x8 wfr[2];
        #pragma unroll
        for (int mtl = 0; mtl < 2; ++mtl)
            wfr[mtl] = *(const bf16x8*)(W1p + (((size_t)(2 * w + mtl) * KS1 + ks) * 64 + lane) * 8);
        bf16x8 xfr[4];
        #pragma unroll
        for (int nt = 0; nt < 4; ++nt)
            xfr[nt] = *(const bf16x8*)(xs + (nt * 16 + lr) * HPITCH + ks * 32 + 8 * lg);
        #pragma unroll
        for (int mtl = 0; mtl < 2; ++mtl)
            #pragma unroll
            for (int nt = 0; nt < 4; ++nt)
                acc1[mtl][nt] = __builtin_amdgcn_mfma_f32_16x16x32_bf16(wfr[mtl], xfr[nt], acc1[mtl][nt], 0, 0, 0);
    }

    // per-lane hidden-dim constants: h = 16*(2w+mtl) + 4*lg + r, r=0..3
    f32x4 b1q[2], b2q[2];
    #pragma unroll
    for (int mtl = 0; mtl < 2; ++mtl) {
        int h0 = 16 * (2 * w + mtl) + 4 * lg;
        b1q[mtl] = *(const f32x4*)&b1[h0];
        b2q[mtl] = *(const f32x4*)&b2[h0];
    }
    const float b30 = b3[0], b31 = b3[1], b32 = b3[2];

    __syncthreads();   // all x reads done (L1 complete everywhere)

    // ---- prologue: h1(0) -> buf1 ----
    #pragma unroll
    for (int mtl = 0; mtl < 2; ++mtl) {
        int h0 = 16 * (2 * w + mtl) + 4 * lg;
        f32x4 ohq = *(const f32x4*)&W1[(size_t)178 * HID + h0];   // k = 0
        #pragma unroll
        for (int nt = 0; nt < 4; ++nt) {
            ushort4 p;
            p.x = f2bf(fmaxf(acc1[mtl][nt][0] + b1q[mtl][0] + ohq[0], 0.0f));
            p.y = f2bf(fmaxf(acc1[mtl][nt][1] + b1q[mtl][1] + ohq[1], 0.0f));
            p.z = f2bf(fmaxf(acc1[mtl][nt][2] + b1q[mtl][2] + ohq[2], 0.0f));
            p.w = f2bf(fmaxf(acc1[mtl][nt][3] + b1q[mtl][3] + ohq[3], 0.0f));
            *(ushort4*)(buf1 + (nt * 16 + lr) * HPITCH + h0) = p;
        }
    }
    __syncthreads();   // h1(0) ready

    // ---- k-loop (2 barriers per k) ----
    for (int k = 0; k < nk; ++k) {
        u16* cur = (k & 1) ? buf0 : buf1;   // h1(k)
        u16* nxt = (k & 1) ? buf1 : buf0;   // target for h1(k+1)

        // pipelined: write h1(k+1) -> nxt (depends only on acc1; ds_writes
        // drain while layer-2's global fragment loads + MFMAs run below)
        if (k + 1 < nk) {
            #pragma unroll
            for (int mtl = 0; mtl < 2; ++mtl) {
                int h0 = 16 * (2 * w + mtl) + 4 * lg;
                f32x4 ohq = *(const f32x4*)&W1[(size_t)(178 + k + 1) * HID + h0];
                #pragma unroll
                for (int nt = 0; nt < 4; ++nt) {
                    ushort4 p;
                    p.x = f2bf(fmaxf(acc1[mtl][nt][0] + b1q[mtl][0] + ohq[0], 0.0f));
                    p.y = f2bf(fmaxf(acc1[mtl][nt][1] + b1q[mtl][1] + ohq[1], 0.0f));
                    p.z = f2bf(fmaxf(acc1[mtl][nt][2] + b1q[mtl][2] + ohq[2], 0.0f));
                    p.w = f2bf(fmaxf(acc1[mtl][nt][3] + b1q[mtl][3] + ohq[3], 0.0f));
                    *(ushort4*)(nxt + (nt * 16 + lr) * HPITCH + h0) = p;
                }
            }
        }

        // layer 2: acc2 = W2^T . h1(k)^T
        f32x4 acc2[2][4];
        #pragma unroll
        for (int a = 0; a < 2; ++a)
            #pragma unroll
            for (int b = 0; b < 4; ++b)
                acc2[a][b] = (f32x4){0.f, 0.f, 0.f, 0.f};

        for (int ks = 0; ks < KS2; ++ks) {
            bf16x8 wfr[2];
            #pragma unroll
            for (int mtl = 0; mtl < 2; ++mtl)
                wfr[mtl] = *(const bf16x8*)(W2p + (((size_t)(2 * w + mtl) * KS2 + ks) * 64 + lane) * 8);
            bf16x8 hfr[4];
            #pragma unroll
            for (int nt = 0; nt < 4; ++nt)
                hfr[nt] = *(const bf16x8*)(cur + (nt * 16 + lr) * HPITCH + ks * 32 + 8 * lg);
            #pragma unroll
            for (int mtl = 0; mtl < 2; ++mtl)
                #pragma unroll
                for (int nt = 0; nt < 4; ++nt)
                    acc2[mtl][nt] = __builtin_amdgcn_mfma_f32_16x16x32_bf16(wfr[mtl], hfr[nt], acc2[mtl][nt], 0, 0, 0);
        }

        // h2 = relu(acc2 + b2) -> hsB (own buffer; prev L3's hsB reads
        // finished at the post-L3 barrier)
        #pragma unroll
        for (int mtl = 0; mtl < 2; ++mtl) {
            int h0 = 16 * (2 * w + mtl) + 4 * lg;
            #pragma unroll
            for (int nt = 0; nt < 4; ++nt) {
                ushort4 p;
                p.x = f2bf(fmaxf(acc2[mtl][nt][0] + b2q[mtl][0], 0.0f));
                p.y = f2bf(fmaxf(acc2[mtl][nt][1] + b2q[mtl][1], 0.0f));
                p.z = f2bf(fmaxf(acc2[mtl][nt][2] + b2q[mtl][2], 0.0f));
                p.w = f2bf(fmaxf(acc2[mtl][nt][3] + b2q[mtl][3], 0.0f));
                *(ushort4*)(hsB + (nt * 16 + lr) * HPITCH + h0) = p;
            }
        }
        __syncthreads();   // h2 ready; h1(k+1) ready

        // layer 3 split across ALL waves: wave (a3=w&3, half=w>>2) computes
        // K-half [128*half, 128*half+128) of logits^T for pairs 16a3..16a3+15.
        const int a3 = w & 3;
        f32x4 acc3 = (f32x4){0.f, 0.f, 0.f, 0.f};
        {
            const int ks0 = (w >> 2) * 4;
            #pragma unroll
            for (int kss = 0; kss < 4; ++kss) {
                int ks = ks0 + kss;
                bf16x8 hfr = *(const bf16x8*)(hsB + (a3 * 16 + lr) * HPITCH + ks * 32 + 8 * lg);
                bf16x8 wfr = *(const bf16x8*)(W3p + ((size_t)(ks * 64 + lane)) * 8);
                acc3 = __builtin_amdgcn_mfma_f32_16x16x32_bf16(wfr, hfr, acc3, 0, 0, 0);
            }
            if (w >= 4 && lg == 0) {   // stash upper-half partial logits
                s_l3[a3][lr][0] = acc3[0];
                s_l3[a3][lr][1] = acc3[1];
                s_l3[a3][lr][2] = acc3[2];
            }
        }
        __syncthreads();   // publishes s_l3; hsB reads done; buffers reusable

        // lower waves: combine halves + softmax + store
        // (safe vs next k: upper waves' next stash happens only after the
        //  next "h2 ready" barrier, which all waves must reach first)
        if (w < 4) {
            int m = 16 * a3 + lr;
            if (lg == 0 && s_val[m]) {
                float l0 = acc3[0] + s_l3[a3][lr][0] + b30;
                float l1 = acc3[1] + s_l3[a3][lr][1] + b31;
                float l2 = acc3[2] + s_l3[a3][lr][2] + b32;
                float mx = fmaxf(l0, fmaxf(l1, l2));
                float e0 = expf(l0 - mx), e1 = expf(l1 - mx), e2 = expf(l2 - mx);
                float inv = 1.0f / (e0 + e1 + e2);
                float p0 = e0 * inv, p1 = e1 * inv, p2 = e2 * inv;
                size_t base = ((size_t)t * E + s_e[m]) * 9;
                if (t == 0) {
                    #pragma unroll
                    for (int kb = 0; kb < 3; ++kb) {
                        cond[base + kb * 3 + 0] = p0;
                        cond[base + kb * 3 + 1] = p1;
                        cond[base + kb * 3 + 2] = p2;
                    }
                } else {
                    cond[base + k * 3 + 0] = p0;
                    cond[base + k * 3 + 1] = p1;
                    cond[base + k * 3 + 2] = p2;
                }
            }
        }
    }
}

// ---------------------------------------------------------------------------
// Marginal chain: m_t = m_{t-1} @ cond[t]
// ---------------------------------------------------------------------------
__global__ __launch_bounds__(256)
void mfp_marg_kernel(const float* __restrict__ cond,
                     float* __restrict__ marg,
                     int E, int T)
{
    int e = blockIdx.x * 256 + threadIdx.x;
    if (e >= E) return;
    const float* c0 = &cond[(size_t)e * 9];
    float m0 = c0[0], m1 = c0[1], m2 = c0[2];
    marg[(size_t)e * 3 + 0] = m0;
    marg[(size_t)e * 3 + 1] = m1;
    marg[(size_t)e * 3 + 2] = m2;
    for (int t = 1; t <= T; ++t) {
        const float* c9 = &cond[((size_t)t * E + e) * 9];
        float n0 = m0 * c9[0] + m1 * c9[3] + m2 * c9[6];
        float n1 = m0 * c9[1] + m1 * c9[4] + m2 * c9[7];
        float n2 = m0 * c9[2] + m1 * c9[5] + m2 * c9[8];
        m0 = n0; m1 = n1; m2 = n2;
        float* mo = &marg[((size_t)t * E + e) * 3];
        mo[0] = m0; mo[1] = m1; mo[2] = m2;
    }
}

// ---------------------------------------------------------------------------
extern "C" void kernel_launch(void* const* d_in, const int* in_sizes, int n_in,
                              void* d_out, int out_size, void* d_ws, size_t ws_size,
                              hipStream_t stream) {
    const float* features  = (const float*)d_in[0];
    const float* states    = (const float*)d_in[1];
    const float* distances = (const float*)d_in[2];
    const float* W1 = (const float*)d_in[3];
    const float* b1 = (const float*)d_in[4];
    const float* W2 = (const float*)d_in[5];
    const float* b2 = (const float*)d_in[6];
    const float* W3 = (const float*)d_in[7];
    const float* b3 = (const float*)d_in[8];
    const int* pairs_i = (const int*)d_in[9];
    const int* pairs_j = (const int*)d_in[10];

    const int N   = in_sizes[0] / D_F;             // 2000
    const int T1s = in_sizes[1] / (N * 5);         // 11
    const int E   = in_sizes[9];                   // 100000
    const int T   = out_size / (12 * E) - 1;       // 10

    float* cond = (float*)d_out;                            // (T+1, E, 3, 3)
    float* marg = (float*)d_out + (size_t)(T + 1) * E * 9;  // (T+1, E, 3)

    u16* W1p = (u16*)d_ws;                                  // 16*KS1*64*8 elems
    u16* W2p = W1p + 16 * KS1 * 64 * 8;                     // 16*KS2*64*8 elems
    u16* W3p = W2p + 16 * KS2 * 64 * 8;                     // KS2*64*8 elems

    {
        int g1 = 16 * KS1 * 64;
        int g2 = 16 * KS2 * 64;
        int g3 = KS2 * 64;
        pack_w_kernel<<<(g1 + 255) / 256, 256, 0, stream>>>(W1, W1p, IN_F, KS1);
        pack_w_kernel<<<(g2 + 255) / 256, 256, 0, stream>>>(W2, W2p, HID, KS2);
        pack_w3_kernel<<<(g3 + 255) / 256, 256, 0, stream>>>(W3, W3p);
    }

    dim3 grid((E + BM - 1) / BM, T + 1);
    const size_t lds_bytes = (size_t)3 * BM * HPITCH * sizeof(u16);   // 101376 B

    mfp_mlp_mfma<<<grid, BLK, lds_bytes, stream>>>(
        features, states, distances, W1, W1p, b1, W2p, b2, W3p, b3,
        pairs_i, pairs_j, cond, N, T1s, E, T);

    mfp_marg_kernel<<<(E + 255) / 256, 256, 0, stream>>>(cond, marg, E, T);
}